// Round 13
// baseline (465.836 us; speedup 1.0000x reference)
//
#include <hip/hip_runtime.h>
#include <hip/hip_bf16.h>
#include <math.h>

#define NN   8192
#define TT   32
#define DIN  4096
#define MME  1024
#define NNZK 131072
#define EPSV 1e-5f
#define MALL (NN + MME)
#define NSLOT 8
#define SLOTREG (NSLOT*256)

typedef __attribute__((ext_vector_type(8))) short bf16x8;
typedef __attribute__((ext_vector_type(4))) float f32x4;

__device__ __forceinline__ float lrelu(float v){ return v > 0.f ? v : 0.2f*v; }
__device__ __forceinline__ short f2b(float f){
    union { __hip_bfloat16 h; short s; } u; u.h = __float2bfloat16(f); return u.s;
}
__device__ __forceinline__ float b2f(short s){
    union { float f; unsigned u; } u; u.u = ((unsigned)(unsigned short)s) << 16; return u.f;
}

// ---------------------------------------------------------------- zero everything small
__global__ void zero_all(int* __restrict__ cnt, int n1, float* __restrict__ slots, int n2){
    int i = blockIdx.x*256 + threadIdx.x;
    if (i < n1) cnt[i] = 0;
    int j = i - n1;
    if (j >= 0 && j < n2) slots[j] = 0.f;
}

// ---------------------------------------------------------------- x -> bf16 (pure stream)
__global__ __launch_bounds__(256) void convert_x(const float4* __restrict__ x,
                                                 bf16x8* __restrict__ xb, int n8){
    int stride = gridDim.x*256;
    for (int i = blockIdx.x*256 + threadIdx.x; i < n8; i += stride){
        float4 lo = x[2*i], hi = x[2*i+1];
        bf16x8 v;
        v[0]=f2b(lo.x); v[1]=f2b(lo.y); v[2]=f2b(lo.z); v[3]=f2b(lo.w);
        v[4]=f2b(hi.x); v[5]=f2b(hi.y); v[6]=f2b(hi.z); v[7]=f2b(hi.w);
        xb[i] = v;
    }
}

// ---------------------------------------------------------------- count + weight converts
__device__ void wconv_body(const float* __restrict__ W, __hip_bfloat16* __restrict__ BT,
                           int K, int N, int gx, int gy){
    __shared__ float tile[32][33];
    int k0 = gy*32, n0 = gx*32;
    int tx = threadIdx.x & 31, ty = threadIdx.x >> 5;
    for (int i = ty; i < 32; i += 8) tile[i][tx] = W[(size_t)(k0+i)*N + n0+tx];
    __syncthreads();
    for (int i = ty; i < 32; i += 8)
        BT[(size_t)(n0+i)*K + k0 + tx] = __float2bfloat16(tile[tx][i]);
}

// blocks [0,512): count_seg | [512,1616): weight converts
__global__ __launch_bounds__(256) void setup_misc(
    const int* __restrict__ he_n, const int* __restrict__ he_e,
    int* __restrict__ ncnt, int* __restrict__ ecnt,
    const float* W1, __hip_bfloat16* W1T, const float* Wh1, __hip_bfloat16* Wh1T,
    const float* Wh2, __hip_bfloat16* Wh2T, const float* W3, __hip_bfloat16* W3T)
{
    int b = blockIdx.x;
    if (b < 512){
        int k = b*256 + threadIdx.x;
        if (k < NNZK){ atomicAdd(&ecnt[he_e[k]], 1); atomicAdd(&ncnt[he_n[k]], 1); }
    } else {
        int c = b - 512;
        if (c < 512)            wconv_body(W1,  W1T,  DIN, 128, c % 4,   c / 4);
        else if (c < 576){ c -= 512; wconv_body(Wh1, Wh1T, 128, 512, c % 16, c / 16); }
        else if (c < 592){ c -= 576; wconv_body(Wh2, Wh2T, 128, 128, c % 4,  c / 4); }
        else             { c -= 592; wconv_body(W3,  W3T,  128, DIN, c % 128, c / 128); }
    }
}

// ---------------------------------------------------------------- CSR pieces
__device__ void scan_body(const int* __restrict__ cnt, int* __restrict__ off,
                          int* __restrict__ cur, int n){
    int t = threadIdx.x;
    int lane = t & 63, wv = t >> 6;
    int chunk = n >> 10;
    int base = t*chunk;
    int s = 0;
#pragma unroll 4
    for (int i = 0; i < chunk; i++) s += cnt[base+i];
    int v = s;
    for (int d = 1; d < 64; d <<= 1){
        int u = __shfl_up(v, d);
        if (lane >= d) v += u;
    }
    __shared__ int wsum[16];
    if (lane == 63) wsum[wv] = v;
    __syncthreads();
    if (wv == 0 && lane < 16){
        int w2 = wsum[lane];
        for (int d = 1; d < 16; d <<= 1){
            int u = __shfl_up(w2, d);
            if (lane >= d) w2 += u;
        }
        wsum[lane] = w2;
    }
    __syncthreads();
    int excl = v - s + (wv > 0 ? wsum[wv-1] : 0);
    for (int i = 0; i < chunk; i++){
        off[base+i] = excl;
        cur[base+i] = excl;
        excl += cnt[base+i];
    }
    if (t == 1023) off[n] = excl;
}

__global__ void scan2(const int* ecnt, int* eoffb, int* ecur,
                      const int* ncnt, int* noffb, int* ncur){
    if (blockIdx.x == 0) scan_body(ecnt, eoffb, ecur, MME);
    else                 scan_body(ncnt, noffb, ncur, NN);
}

__global__ void fill_both(const int* __restrict__ he_n, const int* __restrict__ he_e,
                          int* __restrict__ ecur, int* __restrict__ ncur,
                          int* __restrict__ eperm, int* __restrict__ enode,
                          int* __restrict__ nperm, int* __restrict__ nedge){
    int k = blockIdx.x*256 + threadIdx.x;
    if (k < NNZK){
        int e = he_e[k], n = he_n[k];
        int p = atomicAdd(&ecur[e], 1); eperm[p] = k; enode[p] = n;
        int q = atomicAdd(&ncur[n], 1); nperm[q] = k; nedge[q] = e;
    }
}

#define SWZ(b) ((b) ^ ((((b) >> 6) & 7) << 4))

// ---------------------------------------------------------------- all-bf16 GEMM (GEMM1)
__global__ __launch_bounds__(256) void gemm_bb(
    const __hip_bfloat16* __restrict__ Ab, const __hip_bfloat16* __restrict__ Bwt,
    __hip_bfloat16* __restrict__ Cb, int M, int N, int K, int kchunk)
{
    __shared__ f32x4 WsRaw[512];
    __shared__ f32x4 XsRaw[512];
    char* Ws = (char*)WsRaw;
    char* Xs = (char*)XsRaw;
    const int tid = threadIdx.x;
    const int lane = tid & 63;
    const int w = tid >> 6;
    const int m0 = blockIdx.y << 7, n0 = blockIdx.x << 7;
    const int kz = blockIdx.z * kchunk;
    const int wN = (w >> 1) << 6, wM = (w & 1) << 6;

    const int s0 = tid, s1 = tid + 256;
    const int r0 = s0 >> 2, k0b = (s0 & 3) << 3;
    const int r1 = s1 >> 2, k1b = (s1 & 3) << 3;
    const __hip_bfloat16* pA0 = Ab + (size_t)(m0 + r0)*K + kz + k0b;
    const __hip_bfloat16* pA1 = Ab + (size_t)(m0 + r1)*K + kz + k1b;
    const __hip_bfloat16* pW0 = Bwt + (size_t)(n0 + r0)*K + kz + k0b;
    const __hip_bfloat16* pW1 = Bwt + (size_t)(n0 + r1)*K + kz + k1b;
    const int wo0 = SWZ(s0 << 4), wo1 = SWZ(s1 << 4);

    int rwOff[4], rxOff[4];
#pragma unroll
    for (int f = 0; f < 4; f++){
        rwOff[f] = SWZ((wN + f*16 + (lane & 15))*64 + ((lane >> 4) << 4));
        rxOff[f] = SWZ((wM + f*16 + (lane & 15))*64 + ((lane >> 4) << 4));
    }

    f32x4 acc[4][4] = {};

    bf16x8 a0 = *(const bf16x8*)pA0, a1 = *(const bf16x8*)pA1;
    bf16x8 w0 = *(const bf16x8*)pW0, w1 = *(const bf16x8*)pW1;

    const int nsteps = kchunk >> 5;
    for (int ks = 0; ks < nsteps; ks++){
        __syncthreads();
        *(bf16x8*)(Xs + wo0) = a0;
        *(bf16x8*)(Xs + wo1) = a1;
        *(bf16x8*)(Ws + wo0) = w0;
        *(bf16x8*)(Ws + wo1) = w1;
        __syncthreads();
        if (ks + 1 < nsteps){
            pA0 += 32; pA1 += 32; pW0 += 32; pW1 += 32;
            a0 = *(const bf16x8*)pA0; a1 = *(const bf16x8*)pA1;
            w0 = *(const bf16x8*)pW0; w1 = *(const bf16x8*)pW1;
        }
        bf16x8 wf[4], xf[4];
#pragma unroll
        for (int f = 0; f < 4; f++){
            wf[f] = *(const bf16x8*)(Ws + rwOff[f]);
            xf[f] = *(const bf16x8*)(Xs + rxOff[f]);
        }
#pragma unroll
        for (int i = 0; i < 4; i++)
#pragma unroll
            for (int j = 0; j < 4; j++)
                acc[i][j] = __builtin_amdgcn_mfma_f32_16x16x32_bf16(wf[i], xf[j], acc[i][j], 0, 0, 0);
    }

    const int mc = wM + (lane & 15);
    const int ncb = wN + ((lane >> 4) << 2);
    __hip_bfloat16* Cz = Cb + (size_t)blockIdx.z * ((size_t)M * (size_t)N);
#pragma unroll
    for (int j = 0; j < 4; j++){
        int row = m0 + mc + j*16;
#pragma unroll
        for (int i = 0; i < 4; i++){
            int col = n0 + ncb + i*16;
            f32x4 v = acc[i][j];
            short4 sv = { f2b(v[0]), f2b(v[1]), f2b(v[2]), f2b(v[3]) };
            *(short4*)&Cz[(size_t)row*N + col] = sv;
        }
    }
}

// ---------------------------------------------------------------- GEMM with fused row-attention dot
template<int H>
__global__ __launch_bounds__(256) void gemm_att(
    const float* __restrict__ Aact, const __hip_bfloat16* __restrict__ Bwt,
    __hip_bfloat16* __restrict__ Cb, const float* __restrict__ attv,
    float* __restrict__ axo, float* __restrict__ aeo, int M, int N, int K)
{
    __shared__ f32x4 WsRaw[512];
    __shared__ f32x4 XsRaw[512];
    __shared__ float sAx[128];
    char* Ws = (char*)WsRaw;
    char* Xs = (char*)XsRaw;
    const int tid = threadIdx.x;
    const int lane = tid & 63;
    const int w = tid >> 6;
    const int m0 = blockIdx.y << 7, n0 = blockIdx.x << 7;
    const int wN = (w >> 1) << 6, wM = (w & 1) << 6;

    const int s0 = tid, s1 = tid + 256;
    const int r0 = s0 >> 2, k0b = (s0 & 3) << 3;
    const int r1 = s1 >> 2, k1b = (s1 & 3) << 3;
    const float* pX0 = Aact + (size_t)(m0 + r0)*K + k0b;
    const float* pX1 = Aact + (size_t)(m0 + r1)*K + k1b;
    const __hip_bfloat16* pW0 = Bwt + (size_t)(n0 + r0)*K + k0b;
    const __hip_bfloat16* pW1 = Bwt + (size_t)(n0 + r1)*K + k1b;
    const int wo0 = SWZ(s0 << 4), wo1 = SWZ(s1 << 4);

    int rwOff[4], rxOff[4];
#pragma unroll
    for (int f = 0; f < 4; f++){
        rwOff[f] = SWZ((wN + f*16 + (lane & 15))*64 + ((lane >> 4) << 4));
        rxOff[f] = SWZ((wM + f*16 + (lane & 15))*64 + ((lane >> 4) << 4));
    }

    f32x4 acc[4][4] = {};

    float4 x0l = *(const float4*)pX0, x0h = *(const float4*)(pX0+4);
    float4 x1l = *(const float4*)pX1, x1h = *(const float4*)(pX1+4);
    bf16x8 w0 = *(const bf16x8*)pW0, w1 = *(const bf16x8*)pW1;

    const int nsteps = K >> 5;
    for (int ks = 0; ks < nsteps; ks++){
        bf16x8 vx0, vx1;
        vx0[0]=f2b(x0l.x); vx0[1]=f2b(x0l.y); vx0[2]=f2b(x0l.z); vx0[3]=f2b(x0l.w);
        vx0[4]=f2b(x0h.x); vx0[5]=f2b(x0h.y); vx0[6]=f2b(x0h.z); vx0[7]=f2b(x0h.w);
        vx1[0]=f2b(x1l.x); vx1[1]=f2b(x1l.y); vx1[2]=f2b(x1l.z); vx1[3]=f2b(x1l.w);
        vx1[4]=f2b(x1h.x); vx1[5]=f2b(x1h.y); vx1[6]=f2b(x1h.z); vx1[7]=f2b(x1h.w);
        __syncthreads();
        *(bf16x8*)(Xs + wo0) = vx0;
        *(bf16x8*)(Xs + wo1) = vx1;
        *(bf16x8*)(Ws + wo0) = w0;
        *(bf16x8*)(Ws + wo1) = w1;
        __syncthreads();
        if (ks + 1 < nsteps){
            pX0 += 32; pX1 += 32; pW0 += 32; pW1 += 32;
            x0l = *(const float4*)pX0; x0h = *(const float4*)(pX0+4);
            x1l = *(const float4*)pX1; x1h = *(const float4*)(pX1+4);
            w0 = *(const bf16x8*)pW0;  w1 = *(const bf16x8*)pW1;
        }
        bf16x8 wf[4], xf[4];
#pragma unroll
        for (int f = 0; f < 4; f++){
            wf[f] = *(const bf16x8*)(Ws + rwOff[f]);
            xf[f] = *(const bf16x8*)(Xs + rxOff[f]);
        }
#pragma unroll
        for (int i = 0; i < 4; i++)
#pragma unroll
            for (int j = 0; j < 4; j++)
                acc[i][j] = __builtin_amdgcn_mfma_f32_16x16x32_bf16(wf[i], xf[j], acc[i][j], 0, 0, 0);
    }

    const int mc = wM + (lane & 15);
    const int ncb = wN + ((lane >> 4) << 2);
    if (tid < 128) sAx[tid] = 0.f;
    __syncthreads();
    const int h = blockIdx.x;
    const int aoff = (m0 >= NN) ? 128 : 0;
    const float* av = attv + h*256 + aoff;
    float4 a4[4];
#pragma unroll
    for (int i = 0; i < 4; i++) a4[i] = *(const float4*)&av[ncb + i*16];
    float sj[4] = {0.f, 0.f, 0.f, 0.f};
#pragma unroll
    for (int j = 0; j < 4; j++){
        int row = m0 + mc + j*16;
#pragma unroll
        for (int i = 0; i < 4; i++){
            int col = n0 + ncb + i*16;
            f32x4 v = acc[i][j];
            short4 sv = { f2b(v[0]), f2b(v[1]), f2b(v[2]), f2b(v[3]) };
            *(short4*)&Cb[(size_t)row*N + col] = sv;
            sj[j] += v[0]*a4[i].x + v[1]*a4[i].y + v[2]*a4[i].z + v[3]*a4[i].w;
        }
    }
#pragma unroll
    for (int j = 0; j < 4; j++) atomicAdd(&sAx[mc + j*16], sj[j]);
    __syncthreads();
    if (tid < 128){
        int row = m0 + tid;
        float val = sAx[tid];
        if (row < NN) axo[row*H + h] = val;
        else          aeo[(row - NN)*H + h] = val;
    }
}

// ---------------------------------------------------------------- GEMM3: BN3 fold in staging, y = lrelu(.)+xb epilogue
__global__ __launch_bounds__(256) void gemm_nt8(
    const float* __restrict__ Aact, const __hip_bfloat16* __restrict__ Bwt,
    const __hip_bfloat16* __restrict__ xb, __hip_bfloat16* __restrict__ Yb,
    const float* __restrict__ bias, const float* __restrict__ coefA, int M, int N, int K)
{
    __shared__ f32x4 WsRaw[512];
    __shared__ f32x4 XsRaw[512];
    char* Ws = (char*)WsRaw;
    char* Xs = (char*)XsRaw;
    const int tid = threadIdx.x;
    const int lane = tid & 63;
    const int w = tid >> 6;
    const int m0 = blockIdx.y << 7, n0 = blockIdx.x << 7;
    const int wN = (w >> 1) << 6, wM = (w & 1) << 6;

    const int s0 = tid, s1 = tid + 256;
    const int r0 = s0 >> 2, k0b = (s0 & 3) << 3;
    const int r1 = s1 >> 2, k1b = (s1 & 3) << 3;
    const float* pX0 = Aact + (size_t)(m0 + r0)*K + k0b;
    const float* pX1 = Aact + (size_t)(m0 + r1)*K + k1b;
    const __hip_bfloat16* pW0 = Bwt + (size_t)(n0 + r0)*K + k0b;
    const __hip_bfloat16* pW1 = Bwt + (size_t)(n0 + r1)*K + k1b;
    const int wo0 = SWZ(s0 << 4), wo1 = SWZ(s1 << 4);

    int rwOff[4], rxOff[4];
#pragma unroll
    for (int f = 0; f < 4; f++){
        rwOff[f] = SWZ((wN + f*16 + (lane & 15))*64 + ((lane >> 4) << 4));
        rxOff[f] = SWZ((wM + f*16 + (lane & 15))*64 + ((lane >> 4) << 4));
    }

    f32x4 acc[4][4] = {};

    float4 x0l = *(const float4*)pX0, x0h = *(const float4*)(pX0+4);
    float4 x1l = *(const float4*)pX1, x1h = *(const float4*)(pX1+4);
    bf16x8 w0 = *(const bf16x8*)pW0, w1 = *(const bf16x8*)pW1;

    const int nsteps = K >> 5;
    for (int ks = 0; ks < nsteps; ks++){
        int kc0 = k0b + ks*32, kc1 = k1b + ks*32;
        float4 s0v = *(const float4*)&coefA[kc0],     s0w = *(const float4*)&coefA[kc0+4];
        float4 h0v = *(const float4*)&coefA[128+kc0], h0w = *(const float4*)&coefA[128+kc0+4];
        float4 s1v = *(const float4*)&coefA[kc1],     s1w = *(const float4*)&coefA[kc1+4];
        float4 h1v = *(const float4*)&coefA[128+kc1], h1w = *(const float4*)&coefA[128+kc1+4];
        x0l.x = x0l.x*s0v.x + h0v.x; x0l.y = x0l.y*s0v.y + h0v.y;
        x0l.z = x0l.z*s0v.z + h0v.z; x0l.w = x0l.w*s0v.w + h0v.w;
        x0h.x = x0h.x*s0w.x + h0w.x; x0h.y = x0h.y*s0w.y + h0w.y;
        x0h.z = x0h.z*s0w.z + h0w.z; x0h.w = x0h.w*s0w.w + h0w.w;
        x1l.x = x1l.x*s1v.x + h1v.x; x1l.y = x1l.y*s1v.y + h1v.y;
        x1l.z = x1l.z*s1v.z + h1v.z; x1l.w = x1l.w*s1v.w + h1v.w;
        x1h.x = x1h.x*s1w.x + h1w.x; x1h.y = x1h.y*s1w.y + h1w.y;
        x1h.z = x1h.z*s1w.z + h1w.z; x1h.w = x1h.w*s1w.w + h1w.w;
        bf16x8 vx0, vx1;
        vx0[0]=f2b(x0l.x); vx0[1]=f2b(x0l.y); vx0[2]=f2b(x0l.z); vx0[3]=f2b(x0l.w);
        vx0[4]=f2b(x0h.x); vx0[5]=f2b(x0h.y); vx0[6]=f2b(x0h.z); vx0[7]=f2b(x0h.w);
        vx1[0]=f2b(x1l.x); vx1[1]=f2b(x1l.y); vx1[2]=f2b(x1l.z); vx1[3]=f2b(x1l.w);
        vx1[4]=f2b(x1h.x); vx1[5]=f2b(x1h.y); vx1[6]=f2b(x1h.z); vx1[7]=f2b(x1h.w);
        __syncthreads();
        *(bf16x8*)(Xs + wo0) = vx0;
        *(bf16x8*)(Xs + wo1) = vx1;
        *(bf16x8*)(Ws + wo0) = w0;
        *(bf16x8*)(Ws + wo1) = w1;
        __syncthreads();
        if (ks + 1 < nsteps){
            pX0 += 32; pX1 += 32; pW0 += 32; pW1 += 32;
            x0l = *(const float4*)pX0; x0h = *(const float4*)(pX0+4);
            x1l = *(const float4*)pX1; x1h = *(const float4*)(pX1+4);
            w0 = *(const bf16x8*)pW0;  w1 = *(const bf16x8*)pW1;
        }
        bf16x8 wf[4], xf[4];
#pragma unroll
        for (int f = 0; f < 4; f++){
            wf[f] = *(const bf16x8*)(Ws + rwOff[f]);
            xf[f] = *(const bf16x8*)(Xs + rxOff[f]);
        }
#pragma unroll
        for (int i = 0; i < 4; i++)
#pragma unroll
            for (int j = 0; j < 4; j++)
                acc[i][j] = __builtin_amdgcn_mfma_f32_16x16x32_bf16(wf[i], xf[j], acc[i][j], 0, 0, 0);
    }

    const int mc = wM + (lane & 15);
    const int ncb = wN + ((lane >> 4) << 2);
#pragma unroll
    for (int j = 0; j < 4; j++){
        int row = m0 + mc + j*16;
#pragma unroll
        for (int i = 0; i < 4; i++){
            int col = n0 + ncb + i*16;
            f32x4 v = acc[i][j];
            float4 b4 = *(const float4*)&bias[col];
            short4 xv = *(const short4*)&xb[(size_t)row*N + col];
            short4 sv = { f2b(lrelu(v[0] + b4.x) + b2f(xv.x)),
                          f2b(lrelu(v[1] + b4.y) + b2f(xv.y)),
                          f2b(lrelu(v[2] + b4.z) + b2f(xv.z)),
                          f2b(lrelu(v[3] + b4.w) + b2f(xv.w)) };
            *(short4*)&Yb[(size_t)row*N + col] = sv;
        }
    }
}

// split-K reduce (bf16 partials) + bias + lrelu + fused BN stats -> slot region
__global__ void reduce8s(const __hip_bfloat16* __restrict__ part, const float* __restrict__ bias,
                         float* __restrict__ out, int nf4, int parts, float* __restrict__ slots){
    int tid = threadIdx.x;
    int i = blockIdx.x*256 + tid;
    const short4* p4 = (const short4*)part;
    short4 v0 = p4[i];
    float4 s = { b2f(v0.x), b2f(v0.y), b2f(v0.z), b2f(v0.w) };
    for (int z = 1; z < parts; z++){
        short4 p = p4[(size_t)z*nf4 + i];
        s.x += b2f(p.x); s.y += b2f(p.y); s.z += b2f(p.z); s.w += b2f(p.w);
    }
    int c0 = (i & 31) << 2;
    s.x = lrelu(s.x + bias[c0+0]); s.y = lrelu(s.y + bias[c0+1]);
    s.z = lrelu(s.z + bias[c0+2]); s.w = lrelu(s.w + bias[c0+3]);
    ((float4*)out)[i] = s;
    __shared__ float S[128], Q[128];
    if (tid < 128){ S[tid] = 0.f; Q[tid] = 0.f; }
    __syncthreads();
    atomicAdd(&S[c0+0], s.x); atomicAdd(&Q[c0+0], s.x*s.x);
    atomicAdd(&S[c0+1], s.y); atomicAdd(&Q[c0+1], s.y*s.y);
    atomicAdd(&S[c0+2], s.z); atomicAdd(&Q[c0+2], s.z*s.z);
    atomicAdd(&S[c0+3], s.w); atomicAdd(&Q[c0+3], s.w*s.w);
    __syncthreads();
    if (tid < 128){
        int slot = blockIdx.x & (NSLOT-1);
        atomicAdd(&slots[slot*256 + tid], S[tid]);
        atomicAdd(&slots[slot*256 + 128 + tid], Q[tid]);
    }
}

// ---------------------------------------------------------------- BN
__global__ void bn_stats_v2(const float* __restrict__ x, float* __restrict__ slots, int rows){
    int cg = threadIdx.x & 31, rg = threadIdx.x >> 5;
    float4 s = {0,0,0,0}, q = {0,0,0,0};
    for (int r = blockIdx.x*8 + rg; r < rows; r += gridDim.x*8){
        float4 v = ((const float4*)x)[(size_t)r*32 + cg];
        s.x += v.x; q.x += v.x*v.x;
        s.y += v.y; q.y += v.y*v.y;
        s.z += v.z; q.z += v.z*v.z;
        s.w += v.w; q.w += v.w*v.w;
    }
    __shared__ float S[128], Q[128];
    if (threadIdx.x < 128){ S[threadIdx.x] = 0.f; Q[threadIdx.x] = 0.f; }
    __syncthreads();
    int c0 = cg << 2;
    atomicAdd(&S[c0+0], s.x); atomicAdd(&Q[c0+0], q.x);
    atomicAdd(&S[c0+1], s.y); atomicAdd(&Q[c0+1], q.y);
    atomicAdd(&S[c0+2], s.z); atomicAdd(&Q[c0+2], q.z);
    atomicAdd(&S[c0+3], s.w); atomicAdd(&Q[c0+3], q.w);
    __syncthreads();
    if (threadIdx.x < 128){
        int slot = blockIdx.x & (NSLOT-1);
        atomicAdd(&slots[slot*256 + threadIdx.x], S[threadIdx.x]);
        atomicAdd(&slots[slot*256 + 128 + threadIdx.x], Q[threadIdx.x]);
    }
}

// plain finalize (read-only slots; BN3's coef consumed by gemm_nt8)
__global__ void bn_finalize2(const float* __restrict__ slots,
                             const float* __restrict__ g, const float* __restrict__ b,
                             float invR, float* __restrict__ coef){
    int c = threadIdx.x;
    float s = 0.f, q = 0.f;
    for (int k = 0; k < NSLOT; k++){ s += slots[k*256 + c]; q += slots[k*256 + 128 + c]; }
    float m = s*invR;
    float v = q*invR - m*m;
    float sc = g[c]*rsqrtf(v + EPSV);
    coef[c] = sc;
    coef[128 + c] = b[c] - m*sc;
}

// fused finalize + apply: every block derives coef from slots in LDS, then applies
__global__ __launch_bounds__(256) void bn_apply4f(
    float4* __restrict__ x, const float* __restrict__ slots,
    const float* __restrict__ g, const float* __restrict__ b, float invR, size_t n4)
{
    __shared__ float sc[128], sh[128];
    int tid = threadIdx.x;
    if (tid < 128){
        float s = 0.f, q = 0.f;
        for (int k = 0; k < NSLOT; k++){ s += slots[k*256 + tid]; q += slots[k*256 + 128 + tid]; }
        float m = s*invR;
        float v = q*invR - m*m;
        float scale = g[tid]*rsqrtf(v + EPSV);
        sc[tid] = scale;
        sh[tid] = b[tid] - m*scale;
    }
    __syncthreads();
    size_t i = (size_t)blockIdx.x*blockDim.x + tid;
    size_t stride = (size_t)gridDim.x*blockDim.x;
    for (; i < n4; i += stride){
        int c0 = (int)(i & 31) * 4;
        float4 v = x[i];
        v.x = v.x*sc[c0+0] + sh[c0+0];
        v.y = v.y*sc[c0+1] + sh[c0+1];
        v.z = v.z*sc[c0+2] + sh[c0+2];
        v.w = v.w*sc[c0+3] + sh[c0+3];
        x[i] = v;
    }
}

// ---------------------------------------------------------------- final stage streaming on y (bf16)
__global__ __launch_bounds__(256) void final_stats2(
    const bf16x8* __restrict__ yb, float* __restrict__ slots, int n8)
{
    int tid = threadIdx.x;
    float s[8] = {0,0,0,0,0,0,0,0}, q[8] = {0,0,0,0,0,0,0,0};
    int stride = gridDim.x*256;
    for (int i = blockIdx.x*256 + tid; i < n8; i += stride){
        bf16x8 yv = yb[i];
#pragma unroll
        for (int j = 0; j < 8; j++){
            float y = b2f(yv[j]);
            s[j] += y; q[j] += y*y;
        }
    }
    __shared__ float S[128], Q[128];
    if (tid < 128){ S[tid] = 0.f; Q[tid] = 0.f; }
    __syncthreads();
    int c0 = (tid & 15) << 3;
#pragma unroll
    for (int j = 0; j < 8; j++){
        atomicAdd(&S[c0+j], s[j]);
        atomicAdd(&Q[c0+j], q[j]);
    }
    __syncthreads();
    if (tid < 128){
        int slot = blockIdx.x & (NSLOT-1);
        atomicAdd(&slots[slot*256 + tid], S[tid]);
        atomicAdd(&slots[slot*256 + 128 + tid], Q[tid]);
    }
}

// fused finalize + apply for the final BN (stats over (N,T))
__global__ __launch_bounds__(256) void final_apply2f(
    const bf16x8* __restrict__ yb, const float* __restrict__ slots,
    const float* __restrict__ g, const float* __restrict__ b, float invR,
    float4* __restrict__ out, int n8)
{
    __shared__ float scL[128], shL[128];
    int tid = threadIdx.x;
    if (tid < 128){
        float s = 0.f, q = 0.f;
        for (int k = 0; k < NSLOT; k++){ s += slots[k*256 + tid]; q += slots[k*256 + 128 + tid]; }
        float m = s*invR;
        float v = q*invR - m*m;
        float scale = g[tid]*rsqrtf(v + EPSV);
        scL[tid] = scale;
        shL[tid] = b[tid] - m*scale;
    }
    __syncthreads();
    int c0 = (tid & 15) << 3;
    float sc[8], sh[8];
#pragma unroll
    for (int j = 0; j < 8; j++){ sc[j] = scL[c0+j]; sh[j] = shL[c0+j]; }
    int stride = gridDim.x*256;
    for (int i = blockIdx.x*256 + tid; i < n8; i += stride){
        bf16x8 yv = yb[i];
        float4 lo, hi;
        lo.x = b2f(yv[0])*sc[0] + sh[0];
        lo.y = b2f(yv[1])*sc[1] + sh[1];
        lo.z = b2f(yv[2])*sc[2] + sh[2];
        lo.w = b2f(yv[3])*sc[3] + sh[3];
        hi.x = b2f(yv[4])*sc[4] + sh[4];
        hi.y = b2f(yv[5])*sc[5] + sh[5];
        hi.z = b2f(yv[6])*sc[6] + sh[6];
        hi.w = b2f(yv[7])*sc[7] + sh[7];
        out[2*i]   = lo;
        out[2*i+1] = hi;
    }
}

// ---------------------------------------------------------------- segment ops
__global__ void seg_sum_edge(const int* __restrict__ eoff, const int* __restrict__ enode,
                             const float* __restrict__ h, float* __restrict__ out){
    int m = blockIdx.x, t = threadIdx.x;   // 128
    int jg = t >> 5, cq = t & 31;
    int s0 = eoff[m], cnt = eoff[m+1] - s0;
    __shared__ int sn[128];
    __shared__ float4 comb[4][32];
    float4 acc = {0,0,0,0};
    for (int base = 0; base < cnt; base += 128){
        int i = base + t;
        if (i < cnt) sn[t] = enode[s0+i];
        __syncthreads();
        int lim = min(128, cnt - base);
        for (int j = jg; j < lim; j += 4){
            float4 v = *(const float4*)&h[(size_t)sn[j]*128 + cq*4];
            acc.x += v.x; acc.y += v.y; acc.z += v.z; acc.w += v.w;
        }
        __syncthreads();
    }
    comb[jg][cq] = acc;
    __syncthreads();
    if (t < 32){
        float4 a = comb[0][t], b = comb[1][t], c = comb[2][t], d = comb[3][t];
        float4 tot = { a.x+b.x+c.x+d.x, a.y+b.y+c.y+d.y, a.z+b.z+c.z+d.z, a.w+b.w+c.w+d.w };
        *(float4*)&out[(size_t)m*128 + t*4] = tot;
    }
}

// fused softmax + eo, heads=4 (256 threads; eo laid out [m][c][h])
__global__ void seg_soft_eo4(const int* __restrict__ eoff, const int* __restrict__ eperm,
                             const int* __restrict__ enode,
                             const float* __restrict__ ax, const float* __restrict__ ae,
                             float* __restrict__ alpha, const __hip_bfloat16* __restrict__ xt,
                             float* __restrict__ eo){
    int m = blockIdx.x, t = threadIdx.x;   // 256
    int s0 = eoff[m], cnt = eoff[m+1] - s0;
    __shared__ float red[256];
    if (cnt == 0){
        if (t < 128) *(float4*)&eo[(size_t)m*512 + t*4] = (float4){0,0,0,0};
        return;
    }
    float aeh[4];
#pragma unroll
    for (int h = 0; h < 4; h++) aeh[h] = ae[m*4 + h];
    float lmax[4] = {-1e30f, -1e30f, -1e30f, -1e30f};
    for (int i = t; i < cnt; i += 256){
        int k = eperm[s0+i]; int n = enode[s0+i];
#pragma unroll
        for (int h = 0; h < 4; h++){
            float v = lrelu(ax[n*4 + h] + aeh[h]);
            alpha[(size_t)k*4 + h] = v;
            lmax[h] = fmaxf(lmax[h], v);
        }
    }
    float gmax[4];
#pragma unroll
    for (int h = 0; h < 4; h++){
        red[t] = lmax[h]; __syncthreads();
        for (int s = 128; s > 0; s >>= 1){ if (t < s) red[t] = fmaxf(red[t], red[t+s]); __syncthreads(); }
        gmax[h] = red[0]; __syncthreads();
    }
    float lsum[4] = {0.f, 0.f, 0.f, 0.f};
    for (int i = t; i < cnt; i += 256){
        int k = eperm[s0+i];
#pragma unroll
        for (int h = 0; h < 4; h++){
            float ex = __expf(alpha[(size_t)k*4 + h] - gmax[h]);
            alpha[(size_t)k*4 + h] = ex;
            lsum[h] += ex;
        }
    }
    float ginv[4];
#pragma unroll
    for (int h = 0; h < 4; h++){
        red[t] = lsum[h]; __syncthreads();
        for (int s = 128; s > 0; s >>= 1){ if (t < s) red[t] += red[t+s]; __syncthreads(); }
        ginv[h] = 1.f/red[0]; __syncthreads();
    }
    for (int i = t; i < cnt; i += 256){
        int k = eperm[s0+i];
#pragma unroll
        for (int h = 0; h < 4; h++) alpha[(size_t)k*4 + h] *= ginv[h];
    }
    __syncthreads();
    int jpar = t >> 7, cq = t & 127;
    int hq = cq >> 5;
    __shared__ int sn[128];
    __shared__ float sa[128][4];
    __shared__ float comb[256][4];
    float acc[4] = {0.f, 0.f, 0.f, 0.f};
    for (int base = 0; base < cnt; base += 128){
        int i = base + t;
        if (t < 128 && i < cnt){
            sn[t] = enode[s0+i];
            *(float4*)sa[t] = *(const float4*)&alpha[(size_t)eperm[s0+i]*4];
        }
        __syncthreads();
        int lim = min(128, cnt - base);
        for (int j = jpar; j < lim; j += 2){
            const ushort* p = (const ushort*)xt + (size_t)sn[j]*512 + cq*4;
            ushort4 u = *(const ushort4*)p;
            float a = sa[j][hq];
            acc[0] += a*b2f((short)u.x); acc[1] += a*b2f((short)u.y);
            acc[2] += a*b2f((short)u.z); acc[3] += a*b2f((short)u.w);
        }
        __syncthreads();
    }
    comb[t][0] = acc[0]; comb[t][1] = acc[1]; comb[t][2] = acc[2]; comb[t][3] = acc[3];
    __syncthreads();
    if (t < 128){
        float binv = 1.f/(float)cnt;
#pragma unroll
        for (int i2 = 0; i2 < 4; i2++){
            int ch = t*4 + i2;
            int h = ch >> 7, c = ch & 127;
            eo[(size_t)m*512 + c*4 + h] = (comb[t][i2] + comb[t+128][i2]) * binv;
        }
    }
}

// fused softmax + eo, heads=1 (128 threads)
__global__ void seg_soft_eo1(const int* __restrict__ eoff, const int* __restrict__ eperm,
                             const int* __restrict__ enode,
                             const float* __restrict__ ax, const float* __restrict__ ae,
                             float* __restrict__ alpha, const __hip_bfloat16* __restrict__ xt,
                             float* __restrict__ eo){
    int m = blockIdx.x, t = threadIdx.x;   // 128
    int s0 = eoff[m], cnt = eoff[m+1] - s0;
    __shared__ float red[128];
    if (cnt == 0){
        if (t < 32) *(float4*)&eo[(size_t)m*128 + t*4] = (float4){0,0,0,0};
        return;
    }
    float aeh = ae[m];
    float lmax = -1e30f;
    for (int i = t; i < cnt; i += 128){
        int k = eperm[s0+i]; int n = enode[s0+i];
        float v = lrelu(ax[n] + aeh);
        alpha[k] = v;
        lmax = fmaxf(lmax, v);
    }
    red[t] = lmax; __syncthreads();
    for (int s = 64; s > 0; s >>= 1){ if (t < s) red[t] = fmaxf(red[t], red[t+s]); __syncthreads(); }
    float gmax = red[0]; __syncthreads();
    float lsum = 0.f;
    for (int i = t; i < cnt; i += 128){
        int k = eperm[s0+i];
        float ex = __expf(alpha[k] - gmax);
        alpha[k] = ex;
        lsum += ex;
    }
    red[t] = lsum; __syncthreads();
    for (int s = 64; s > 0; s >>= 1){ if (t < s) red[t] += red[t+s]; __syncthreads(); }
    float ginv = 1.f/red[0]; __syncthreads();
    for (int i = t; i < cnt; i += 128){
        int k = eperm[s0+i];
        alpha[k] *= ginv;
    }
    __syncthreads();
    int jg = t >> 5, cq = t & 31;
    __shared__ int sn[128];
    __shared__ float sa[128];
    __shared__ float4 comb[4][32];
    float4 acc = {0,0,0,0};
    for (int base = 0; base < cnt; base += 128){
        int i = base + t;
        if (i < cnt){
            sn[t] = enode[s0+i];
            sa[t] = alpha[eperm[s0+i]];
        }
        __syncthreads();
        int lim = min(128, cnt - base);
        for (int j = jg; j < lim; j += 4){
            const ushort* p = (const ushort*)xt + (size_t)sn[j]*128 + cq*4;
            ushort4 u = *(const ushort4*)p;
            float a = sa[j];
            acc.x += a*b2f((short)u.x); acc.y += a*b2f((short)u.y);
            acc.z += a*b2f((short)u.z); acc.w += a*b2f((short)u.w);
        }
        __syncthreads();
    }
    comb[jg][cq] = acc;
    __syncthreads();
    if (t < 32){
        float binv = 1.f/(float)cnt;
        float4 a = comb[0][t], b = comb[1][t], c = comb[2][t], d = comb[3][t];
        float4 tot = { (a.x+b.x+c.x+d.x)*binv, (a.y+b.y+c.y+d.y)*binv,
                       (a.z+b.z+c.z+d.z)*binv, (a.w+b.w+c.w+d.w)*binv };
        *(float4*)&eo[(size_t)m*128 + t*4] = tot;
    }
}

__global__ void seg_node_out4(const int* __restrict__ noff, const int* __restrict__ nperm,
                              const int* __restrict__ nedge,
                              const float* __restrict__ alpha, const float* __restrict__ eo,
                              const float* __restrict__ hin, const float* __restrict__ bias,
                              float* __restrict__ hout){
    int n = blockIdx.x, c = threadIdx.x;   // 128
    int s0 = noff[n], cnt = noff[n+1] - s0;
    float acc = 0.f;
    for (int i = 0; i < cnt; i++){
        int k = nperm[s0+i]; int e = nedge[s0+i];
        float4 al = *(const float4*)&alpha[(size_t)k*4];
        float4 ev = *(const float4*)&eo[(size_t)e*512 + c*4];
        acc += al.x*ev.x + al.y*ev.y + al.z*ev.z + al.w*ev.w;
    }
    float dinv = cnt > 0 ? 1.f/((float)cnt*4.f) : 0.f;
    hout[(size_t)n*128 + c] = hin[(size_t)n*128 + c] + bias[c] + acc*dinv;
}

__global__ void seg_node_out1(const int* __restrict__ noff, const int* __restrict__ nperm,
                              const int* __restrict__ nedge,
                              const float* __restrict__ alpha, const float* __restrict__ eo,
                              const float* __restrict__ hin, const float* __restrict__ bias,
                              float* __restrict__ hout){
    int n = blockIdx.x, c = threadIdx.x;
    int s0 = noff[n], cnt = noff[n+1] - s0;
    float acc = 0.f;
    for (int i = 0; i < cnt; i++){
        int k = nperm[s0+i]; int e = nedge[s0+i];
        acc += alpha[k]*eo[(size_t)e*128 + c];
    }
    float dinv = cnt > 0 ? 1.f/(float)cnt : 0.f;
    hout[(size_t)n*128 + c] = hin[(size_t)n*128 + c] + bias[c] + acc*dinv;
}

// ---------------------------------------------------------------- launcher
extern "C" void kernel_launch(void* const* d_in, const int* in_sizes, int n_in,
                              void* d_out, int out_size, void* d_ws, size_t ws_size,
                              hipStream_t stream){
    const float* x    = (const float*)d_in[0];
    const int*   he_n = (const int*)  d_in[1];
    const int*   he_e = (const int*)  d_in[2];
    const float* W1   = (const float*)d_in[3];
    const float* b1   = (const float*)d_in[4];
    const float* g1   = (const float*)d_in[5];
    const float* be1  = (const float*)d_in[6];
    const float* Wh1  = (const float*)d_in[7];
    const float* att1 = (const float*)d_in[8];
    const float* bh1  = (const float*)d_in[9];
    const float* g2   = (const float*)d_in[10];
    const float* be2  = (const float*)d_in[11];
    const float* Wh2  = (const float*)d_in[12];
    const float* att2 = (const float*)d_in[13];
    const float* bh2  = (const float*)d_in[14];
    const float* g3   = (const float*)d_in[15];
    const float* be3  = (const float*)d_in[16];
    const float* W3   = (const float*)d_in[17];
    const float* b3   = (const float*)d_in[18];
    const float* g4   = (const float*)d_in[19];
    const float* be4  = (const float*)d_in[20];
    float* out = (float*)d_out;

    char* ws = (char*)d_ws;
    size_t off = 0;
    auto alloc = [&](size_t bytes)->char*{ char* p = ws + off; off += (bytes + 255) & ~(size_t)255; return p; };

    // big region (64 MB): ybuf (final) aliases part (GEMM1) + xt1b (hconv1)
    char* big = alloc((size_t)NN*DIN*2);
    __hip_bfloat16* ybuf = (__hip_bfloat16*)big;
    __hip_bfloat16* part = (__hip_bfloat16*)big;
    __hip_bfloat16* xt1b = (__hip_bfloat16*)(big + (size_t)16*NN*128*2);
    __hip_bfloat16* xbuf = (__hip_bfloat16*)alloc((size_t)NN*DIN*2);

    float* hall1  = (float*)alloc((size_t)MALL*128*4);
    float* hall2  = (float*)alloc((size_t)MALL*128*4);
    float* h3     = (float*)alloc((size_t)NN*128*4);
    __hip_bfloat16* xt2b = (__hip_bfloat16*)alloc((size_t)MALL*128*2);
    float* eo     = (float*)alloc((size_t)MME*512*4);
    float* alpha  = (float*)alloc((size_t)NNZK*4*4);
    float* ax     = (float*)alloc((size_t)NN*4*4);
    float* ae     = (float*)alloc((size_t)MME*4*4);
    float* slots  = (float*)alloc((size_t)4*SLOTREG*4);   // 4 single-use regions
    float* coef   = (float*)alloc(256*4);
    __hip_bfloat16* W1T  = (__hip_bfloat16*)alloc((size_t)128*DIN*2);
    __hip_bfloat16* Wh1T = (__hip_bfloat16*)alloc((size_t)512*128*2);
    __hip_bfloat16* Wh2T = (__hip_bfloat16*)alloc((size_t)128*128*2);
    __hip_bfloat16* W3T  = (__hip_bfloat16*)alloc((size_t)DIN*128*2);
    int* ecnt  = (int*)alloc(MME*4);
    int* ncnt  = (int*)alloc(NN*4);
    int* eoffb = (int*)alloc((MME+1)*4);
    int* ecur  = (int*)alloc(MME*4);
    int* noffb = (int*)alloc((NN+1)*4);
    int* ncur  = (int*)alloc(NN*4);
    int* eperm = (int*)alloc((size_t)NNZK*4);
    int* nperm = (int*)alloc((size_t)NNZK*4);
    int* enode = (int*)alloc((size_t)NNZK*4);
    int* nedge = (int*)alloc((size_t)NNZK*4);

    float* slot0 = slots;
    float* slot1 = slots + SLOTREG;
    float* slot2 = slots + 2*SLOTREG;
    float* slot3 = slots + 3*SLOTREG;

    // ---- zero counters + all slot regions ----
    zero_all<<<(MME+NN+4*SLOTREG+255)/256, 256, 0, stream>>>(ecnt, MME+NN, slots, 4*SLOTREG);

    // ---- streams + misc setup (split: pure stream vs atomics/strided) ----
    convert_x<<<2048, 256, 0, stream>>>((const float4*)x, (bf16x8*)xbuf, NN*DIN/8);
    setup_misc<<<1616, 256, 0, stream>>>(he_n, he_e, ncnt, ecnt,
                                         W1, W1T, Wh1, Wh1T, Wh2, Wh2T, W3, W3T);

    // ---- CSR ----
    scan2<<<2, 1024, 0, stream>>>(ecnt, eoffb, ecur, ncnt, noffb, ncur);
    fill_both<<<NNZK/256, 256, 0, stream>>>(he_n, he_e, ecur, ncur, eperm, enode, nperm, nedge);

    // ---- layer 0 ----
    gemm_bb<<<dim3(1, NN/128, 16), 256, 0, stream>>>(xbuf, W1T, part, NN, 128, DIN, DIN/16);
    reduce8s<<<NN*128/4/256, 256, 0, stream>>>(part, b1, hall1, NN*128/4, 16, slot0);
    bn_apply4f<<<1024, 256, 0, stream>>>((float4*)hall1, slot0, g1, be1, 1.f/NN, (size_t)NN*32);

    // ---- hconv1 (heads=4) ----
    seg_sum_edge<<<MME, 128, 0, stream>>>(eoffb, enode, hall1, hall1 + (size_t)NN*128);
    gemm_att<4><<<dim3(4, MALL/128), 256, 0, stream>>>(hall1, Wh1T, xt1b, att1, ax, ae, MALL, 512, 128);
    seg_soft_eo4<<<MME, 256, 0, stream>>>(eoffb, eperm, enode, ax, ae, alpha, xt1b, eo);
    seg_node_out4<<<NN, 128, 0, stream>>>(noffb, nperm, nedge, alpha, eo, hall1, bh1, hall2);
    bn_stats_v2<<<256, 256, 0, stream>>>(hall2, slot1, NN);
    bn_apply4f<<<1024, 256, 0, stream>>>((float4*)hall2, slot1, g2, be2, 1.f/NN, (size_t)NN*32);

    // ---- hconv2 (heads=1) ----
    seg_sum_edge<<<MME, 128, 0, stream>>>(eoffb, enode, hall2, hall2 + (size_t)NN*128);
    gemm_att<1><<<dim3(1, MALL/128), 256, 0, stream>>>(hall2, Wh2T, xt2b, att2, ax, ae, MALL, 128, 128);
    seg_soft_eo1<<<MME, 128, 0, stream>>>(eoffb, eperm, enode, ax, ae, alpha, xt2b, eo);
    seg_node_out1<<<NN, 128, 0, stream>>>(noffb, nperm, nedge, alpha, eo, hall2, bh2, h3);

    // ---- BN3 stats (apply folded into GEMM3 staging) ----
    bn_stats_v2<<<256, 256, 0, stream>>>(h3, slot2, NN);
    bn_finalize2<<<1, 128, 0, stream>>>(slot2, g3, be3, 1.f/NN, coef);

    // ---- final ----
    gemm_nt8<<<dim3(DIN/128, NN/128), 256, 0, stream>>>(h3, W3T, xbuf, ybuf, b3, coef, NN, DIN, 128);
    final_stats2<<<2048, 256, 0, stream>>>((const bf16x8*)ybuf, slot3, NN*DIN/8);
    final_apply2f<<<2048, 256, 0, stream>>>((const bf16x8*)ybuf, slot3, g4, be4,
                                            1.f/((float)NN*TT), (float4*)out, NN*DIN/8);
}

// Round 14
// 452.136 us; speedup vs baseline: 1.0303x; 1.0303x over previous
//
#include <hip/hip_runtime.h>
#include <hip/hip_bf16.h>
#include <math.h>

#define NN   8192
#define TT   32
#define DIN  4096
#define MME  1024
#define NNZK 131072
#define EPSV 1e-5f
#define MALL (NN + MME)
#define NSLOT 8
#define SLOTREG (NSLOT*256)

typedef __attribute__((ext_vector_type(8))) short bf16x8;
typedef __attribute__((ext_vector_type(4))) float f32x4;

__device__ __forceinline__ float lrelu(float v){ return v > 0.f ? v : 0.2f*v; }
__device__ __forceinline__ short f2b(float f){
    union { __hip_bfloat16 h; short s; } u; u.h = __float2bfloat16(f); return u.s;
}
__device__ __forceinline__ float b2f(short s){
    union { float f; unsigned u; } u; u.u = ((unsigned)(unsigned short)s) << 16; return u.f;
}

// ---------------------------------------------------------------- zero everything small
__global__ void zero_all(int* __restrict__ cnt, int n1, float* __restrict__ slots, int n2){
    int i = blockIdx.x*256 + threadIdx.x;
    if (i < n1) cnt[i] = 0;
    int j = i - n1;
    if (j >= 0 && j < n2) slots[j] = 0.f;
}

// ---------------------------------------------------------------- setup mega-kernel
__device__ void wconv_body(const float* __restrict__ W, __hip_bfloat16* __restrict__ BT,
                           int K, int N, int gx, int gy){
    __shared__ float tile[32][33];
    int k0 = gy*32, n0 = gx*32;
    int tx = threadIdx.x & 31, ty = threadIdx.x >> 5;
    for (int i = ty; i < 32; i += 8) tile[i][tx] = W[(size_t)(k0+i)*N + n0+tx];
    __syncthreads();
    for (int i = ty; i < 32; i += 8)
        BT[(size_t)(n0+i)*K + k0 + tx] = __float2bfloat16(tile[tx][i]);
}

// blocks [0,2048): x->bf16 | [2048,2560): count_seg | [2560,3664): weight converts
__global__ __launch_bounds__(256) void setup_all(
    const float4* __restrict__ x, bf16x8* __restrict__ xb,
    const int* __restrict__ he_n, const int* __restrict__ he_e,
    int* __restrict__ ncnt, int* __restrict__ ecnt,
    const float* W1, __hip_bfloat16* W1T, const float* Wh1, __hip_bfloat16* Wh1T,
    const float* Wh2, __hip_bfloat16* Wh2T, const float* W3, __hip_bfloat16* W3T)
{
    int b = blockIdx.x;
    if (b < 2048){
        const int n8 = NN*DIN/8;
        for (int i = b*256 + threadIdx.x; i < n8; i += 2048*256){
            float4 lo = x[2*i], hi = x[2*i+1];
            bf16x8 v;
            v[0]=f2b(lo.x); v[1]=f2b(lo.y); v[2]=f2b(lo.z); v[3]=f2b(lo.w);
            v[4]=f2b(hi.x); v[5]=f2b(hi.y); v[6]=f2b(hi.z); v[7]=f2b(hi.w);
            xb[i] = v;
        }
    } else if (b < 2560){
        int k = (b - 2048)*256 + threadIdx.x;
        if (k < NNZK){ atomicAdd(&ecnt[he_e[k]], 1); atomicAdd(&ncnt[he_n[k]], 1); }
    } else {
        int c = b - 2560;
        if (c < 512)            wconv_body(W1,  W1T,  DIN, 128, c % 4,   c / 4);
        else if (c < 576){ c -= 512; wconv_body(Wh1, Wh1T, 128, 512, c % 16, c / 16); }
        else if (c < 592){ c -= 576; wconv_body(Wh2, Wh2T, 128, 128, c % 4,  c / 4); }
        else             { c -= 592; wconv_body(W3,  W3T,  128, DIN, c % 128, c / 128); }
    }
}

// ---------------------------------------------------------------- CSR pieces
__device__ void scan_body(const int* __restrict__ cnt, int* __restrict__ off,
                          int* __restrict__ cur, int n){
    int t = threadIdx.x;
    int lane = t & 63, wv = t >> 6;
    int chunk = n >> 10;
    int base = t*chunk;
    int s = 0;
#pragma unroll 4
    for (int i = 0; i < chunk; i++) s += cnt[base+i];
    int v = s;
    for (int d = 1; d < 64; d <<= 1){
        int u = __shfl_up(v, d);
        if (lane >= d) v += u;
    }
    __shared__ int wsum[16];
    if (lane == 63) wsum[wv] = v;
    __syncthreads();
    if (wv == 0 && lane < 16){
        int w2 = wsum[lane];
        for (int d = 1; d < 16; d <<= 1){
            int u = __shfl_up(w2, d);
            if (lane >= d) w2 += u;
        }
        wsum[lane] = w2;
    }
    __syncthreads();
    int excl = v - s + (wv > 0 ? wsum[wv-1] : 0);
    for (int i = 0; i < chunk; i++){
        off[base+i] = excl;
        cur[base+i] = excl;
        excl += cnt[base+i];
    }
    if (t == 1023) off[n] = excl;
}

__global__ void scan2(const int* ecnt, int* eoffb, int* ecur,
                      const int* ncnt, int* noffb, int* ncur){
    if (blockIdx.x == 0) scan_body(ecnt, eoffb, ecur, MME);
    else                 scan_body(ncnt, noffb, ncur, NN);
}

__global__ void fill_both(const int* __restrict__ he_n, const int* __restrict__ he_e,
                          int* __restrict__ ecur, int* __restrict__ ncur,
                          int* __restrict__ eperm, int* __restrict__ enode,
                          int* __restrict__ nperm, int* __restrict__ nedge){
    int k = blockIdx.x*256 + threadIdx.x;
    if (k < NNZK){
        int e = he_e[k], n = he_n[k];
        int p = atomicAdd(&ecur[e], 1); eperm[p] = k; enode[p] = n;
        int q = atomicAdd(&ncur[n], 1); nperm[q] = k; nedge[q] = e;
    }
}

#define SWZ(b) ((b) ^ ((((b) >> 6) & 7) << 4))

// ---------------------------------------------------------------- all-bf16 GEMM (GEMM1)
__global__ __launch_bounds__(256) void gemm_bb(
    const __hip_bfloat16* __restrict__ Ab, const __hip_bfloat16* __restrict__ Bwt,
    __hip_bfloat16* __restrict__ Cb, int M, int N, int K, int kchunk)
{
    __shared__ f32x4 WsRaw[512];
    __shared__ f32x4 XsRaw[512];
    char* Ws = (char*)WsRaw;
    char* Xs = (char*)XsRaw;
    const int tid = threadIdx.x;
    const int lane = tid & 63;
    const int w = tid >> 6;
    const int m0 = blockIdx.y << 7, n0 = blockIdx.x << 7;
    const int kz = blockIdx.z * kchunk;
    const int wN = (w >> 1) << 6, wM = (w & 1) << 6;

    const int s0 = tid, s1 = tid + 256;
    const int r0 = s0 >> 2, k0b = (s0 & 3) << 3;
    const int r1 = s1 >> 2, k1b = (s1 & 3) << 3;
    const __hip_bfloat16* pA0 = Ab + (size_t)(m0 + r0)*K + kz + k0b;
    const __hip_bfloat16* pA1 = Ab + (size_t)(m0 + r1)*K + kz + k1b;
    const __hip_bfloat16* pW0 = Bwt + (size_t)(n0 + r0)*K + kz + k0b;
    const __hip_bfloat16* pW1 = Bwt + (size_t)(n0 + r1)*K + kz + k1b;
    const int wo0 = SWZ(s0 << 4), wo1 = SWZ(s1 << 4);

    int rwOff[4], rxOff[4];
#pragma unroll
    for (int f = 0; f < 4; f++){
        rwOff[f] = SWZ((wN + f*16 + (lane & 15))*64 + ((lane >> 4) << 4));
        rxOff[f] = SWZ((wM + f*16 + (lane & 15))*64 + ((lane >> 4) << 4));
    }

    f32x4 acc[4][4] = {};

    bf16x8 a0 = *(const bf16x8*)pA0, a1 = *(const bf16x8*)pA1;
    bf16x8 w0 = *(const bf16x8*)pW0, w1 = *(const bf16x8*)pW1;

    const int nsteps = kchunk >> 5;
    for (int ks = 0; ks < nsteps; ks++){
        __syncthreads();
        *(bf16x8*)(Xs + wo0) = a0;
        *(bf16x8*)(Xs + wo1) = a1;
        *(bf16x8*)(Ws + wo0) = w0;
        *(bf16x8*)(Ws + wo1) = w1;
        __syncthreads();
        if (ks + 1 < nsteps){
            pA0 += 32; pA1 += 32; pW0 += 32; pW1 += 32;
            a0 = *(const bf16x8*)pA0; a1 = *(const bf16x8*)pA1;
            w0 = *(const bf16x8*)pW0; w1 = *(const bf16x8*)pW1;
        }
        bf16x8 wf[4], xf[4];
#pragma unroll
        for (int f = 0; f < 4; f++){
            wf[f] = *(const bf16x8*)(Ws + rwOff[f]);
            xf[f] = *(const bf16x8*)(Xs + rxOff[f]);
        }
#pragma unroll
        for (int i = 0; i < 4; i++)
#pragma unroll
            for (int j = 0; j < 4; j++)
                acc[i][j] = __builtin_amdgcn_mfma_f32_16x16x32_bf16(wf[i], xf[j], acc[i][j], 0, 0, 0);
    }

    const int mc = wM + (lane & 15);
    const int ncb = wN + ((lane >> 4) << 2);
    __hip_bfloat16* Cz = Cb + (size_t)blockIdx.z * ((size_t)M * (size_t)N);
#pragma unroll
    for (int j = 0; j < 4; j++){
        int row = m0 + mc + j*16;
#pragma unroll
        for (int i = 0; i < 4; i++){
            int col = n0 + ncb + i*16;
            f32x4 v = acc[i][j];
            short4 sv = { f2b(v[0]), f2b(v[1]), f2b(v[2]), f2b(v[3]) };
            *(short4*)&Cz[(size_t)row*N + col] = sv;
        }
    }
}

// ---------------------------------------------------------------- GEMM with fused row-attention dot
template<int H>
__global__ __launch_bounds__(256) void gemm_att(
    const float* __restrict__ Aact, const __hip_bfloat16* __restrict__ Bwt,
    __hip_bfloat16* __restrict__ Cb, const float* __restrict__ attv,
    float* __restrict__ axo, float* __restrict__ aeo, int M, int N, int K)
{
    __shared__ f32x4 WsRaw[512];
    __shared__ f32x4 XsRaw[512];
    __shared__ float sAx[128];
    char* Ws = (char*)WsRaw;
    char* Xs = (char*)XsRaw;
    const int tid = threadIdx.x;
    const int lane = tid & 63;
    const int w = tid >> 6;
    const int m0 = blockIdx.y << 7, n0 = blockIdx.x << 7;
    const int wN = (w >> 1) << 6, wM = (w & 1) << 6;

    const int s0 = tid, s1 = tid + 256;
    const int r0 = s0 >> 2, k0b = (s0 & 3) << 3;
    const int r1 = s1 >> 2, k1b = (s1 & 3) << 3;
    const float* pX0 = Aact + (size_t)(m0 + r0)*K + k0b;
    const float* pX1 = Aact + (size_t)(m0 + r1)*K + k1b;
    const __hip_bfloat16* pW0 = Bwt + (size_t)(n0 + r0)*K + k0b;
    const __hip_bfloat16* pW1 = Bwt + (size_t)(n0 + r1)*K + k1b;
    const int wo0 = SWZ(s0 << 4), wo1 = SWZ(s1 << 4);

    int rwOff[4], rxOff[4];
#pragma unroll
    for (int f = 0; f < 4; f++){
        rwOff[f] = SWZ((wN + f*16 + (lane & 15))*64 + ((lane >> 4) << 4));
        rxOff[f] = SWZ((wM + f*16 + (lane & 15))*64 + ((lane >> 4) << 4));
    }

    f32x4 acc[4][4] = {};

    float4 x0l = *(const float4*)pX0, x0h = *(const float4*)(pX0+4);
    float4 x1l = *(const float4*)pX1, x1h = *(const float4*)(pX1+4);
    bf16x8 w0 = *(const bf16x8*)pW0, w1 = *(const bf16x8*)pW1;

    const int nsteps = K >> 5;
    for (int ks = 0; ks < nsteps; ks++){
        bf16x8 vx0, vx1;
        vx0[0]=f2b(x0l.x); vx0[1]=f2b(x0l.y); vx0[2]=f2b(x0l.z); vx0[3]=f2b(x0l.w);
        vx0[4]=f2b(x0h.x); vx0[5]=f2b(x0h.y); vx0[6]=f2b(x0h.z); vx0[7]=f2b(x0h.w);
        vx1[0]=f2b(x1l.x); vx1[1]=f2b(x1l.y); vx1[2]=f2b(x1l.z); vx1[3]=f2b(x1l.w);
        vx1[4]=f2b(x1h.x); vx1[5]=f2b(x1h.y); vx1[6]=f2b(x1h.z); vx1[7]=f2b(x1h.w);
        __syncthreads();
        *(bf16x8*)(Xs + wo0) = vx0;
        *(bf16x8*)(Xs + wo1) = vx1;
        *(bf16x8*)(Ws + wo0) = w0;
        *(bf16x8*)(Ws + wo1) = w1;
        __syncthreads();
        if (ks + 1 < nsteps){
            pX0 += 32; pX1 += 32; pW0 += 32; pW1 += 32;
            x0l = *(const float4*)pX0; x0h = *(const float4*)(pX0+4);
            x1l = *(const float4*)pX1; x1h = *(const float4*)(pX1+4);
            w0 = *(const bf16x8*)pW0;  w1 = *(const bf16x8*)pW1;
        }
        bf16x8 wf[4], xf[4];
#pragma unroll
        for (int f = 0; f < 4; f++){
            wf[f] = *(const bf16x8*)(Ws + rwOff[f]);
            xf[f] = *(const bf16x8*)(Xs + rxOff[f]);
        }
#pragma unroll
        for (int i = 0; i < 4; i++)
#pragma unroll
            for (int j = 0; j < 4; j++)
                acc[i][j] = __builtin_amdgcn_mfma_f32_16x16x32_bf16(wf[i], xf[j], acc[i][j], 0, 0, 0);
    }

    const int mc = wM + (lane & 15);
    const int ncb = wN + ((lane >> 4) << 2);
    if (tid < 128) sAx[tid] = 0.f;
    __syncthreads();
    const int h = blockIdx.x;
    const int aoff = (m0 >= NN) ? 128 : 0;
    const float* av = attv + h*256 + aoff;
    float4 a4[4];
#pragma unroll
    for (int i = 0; i < 4; i++) a4[i] = *(const float4*)&av[ncb + i*16];
    float sj[4] = {0.f, 0.f, 0.f, 0.f};
#pragma unroll
    for (int j = 0; j < 4; j++){
        int row = m0 + mc + j*16;
#pragma unroll
        for (int i = 0; i < 4; i++){
            int col = n0 + ncb + i*16;
            f32x4 v = acc[i][j];
            short4 sv = { f2b(v[0]), f2b(v[1]), f2b(v[2]), f2b(v[3]) };
            *(short4*)&Cb[(size_t)row*N + col] = sv;
            sj[j] += v[0]*a4[i].x + v[1]*a4[i].y + v[2]*a4[i].z + v[3]*a4[i].w;
        }
    }
#pragma unroll
    for (int j = 0; j < 4; j++) atomicAdd(&sAx[mc + j*16], sj[j]);
    __syncthreads();
    if (tid < 128){
        int row = m0 + tid;
        float val = sAx[tid];
        if (row < NN) axo[row*H + h] = val;
        else          aeo[(row - NN)*H + h] = val;
    }
}

// ---------------------------------------------------------------- GEMM3: BN3 fold in staging, y = lrelu(.)+xb epilogue
__global__ __launch_bounds__(256) void gemm_nt8(
    const float* __restrict__ Aact, const __hip_bfloat16* __restrict__ Bwt,
    const __hip_bfloat16* __restrict__ xb, __hip_bfloat16* __restrict__ Yb,
    const float* __restrict__ bias, const float* __restrict__ coefA, int M, int N, int K)
{
    __shared__ f32x4 WsRaw[512];
    __shared__ f32x4 XsRaw[512];
    char* Ws = (char*)WsRaw;
    char* Xs = (char*)XsRaw;
    const int tid = threadIdx.x;
    const int lane = tid & 63;
    const int w = tid >> 6;
    const int m0 = blockIdx.y << 7, n0 = blockIdx.x << 7;
    const int wN = (w >> 1) << 6, wM = (w & 1) << 6;

    const int s0 = tid, s1 = tid + 256;
    const int r0 = s0 >> 2, k0b = (s0 & 3) << 3;
    const int r1 = s1 >> 2, k1b = (s1 & 3) << 3;
    const float* pX0 = Aact + (size_t)(m0 + r0)*K + k0b;
    const float* pX1 = Aact + (size_t)(m0 + r1)*K + k1b;
    const __hip_bfloat16* pW0 = Bwt + (size_t)(n0 + r0)*K + k0b;
    const __hip_bfloat16* pW1 = Bwt + (size_t)(n0 + r1)*K + k1b;
    const int wo0 = SWZ(s0 << 4), wo1 = SWZ(s1 << 4);

    int rwOff[4], rxOff[4];
#pragma unroll
    for (int f = 0; f < 4; f++){
        rwOff[f] = SWZ((wN + f*16 + (lane & 15))*64 + ((lane >> 4) << 4));
        rxOff[f] = SWZ((wM + f*16 + (lane & 15))*64 + ((lane >> 4) << 4));
    }

    f32x4 acc[4][4] = {};

    float4 x0l = *(const float4*)pX0, x0h = *(const float4*)(pX0+4);
    float4 x1l = *(const float4*)pX1, x1h = *(const float4*)(pX1+4);
    bf16x8 w0 = *(const bf16x8*)pW0, w1 = *(const bf16x8*)pW1;

    const int nsteps = K >> 5;
    for (int ks = 0; ks < nsteps; ks++){
        int kc0 = k0b + ks*32, kc1 = k1b + ks*32;
        float4 s0v = *(const float4*)&coefA[kc0],     s0w = *(const float4*)&coefA[kc0+4];
        float4 h0v = *(const float4*)&coefA[128+kc0], h0w = *(const float4*)&coefA[128+kc0+4];
        float4 s1v = *(const float4*)&coefA[kc1],     s1w = *(const float4*)&coefA[kc1+4];
        float4 h1v = *(const float4*)&coefA[128+kc1], h1w = *(const float4*)&coefA[128+kc1+4];
        x0l.x = x0l.x*s0v.x + h0v.x; x0l.y = x0l.y*s0v.y + h0v.y;
        x0l.z = x0l.z*s0v.z + h0v.z; x0l.w = x0l.w*s0v.w + h0v.w;
        x0h.x = x0h.x*s0w.x + h0w.x; x0h.y = x0h.y*s0w.y + h0w.y;
        x0h.z = x0h.z*s0w.z + h0w.z; x0h.w = x0h.w*s0w.w + h0w.w;
        x1l.x = x1l.x*s1v.x + h1v.x; x1l.y = x1l.y*s1v.y + h1v.y;
        x1l.z = x1l.z*s1v.z + h1v.z; x1l.w = x1l.w*s1v.w + h1v.w;
        x1h.x = x1h.x*s1w.x + h1w.x; x1h.y = x1h.y*s1w.y + h1w.y;
        x1h.z = x1h.z*s1w.z + h1w.z; x1h.w = x1h.w*s1w.w + h1w.w;
        bf16x8 vx0, vx1;
        vx0[0]=f2b(x0l.x); vx0[1]=f2b(x0l.y); vx0[2]=f2b(x0l.z); vx0[3]=f2b(x0l.w);
        vx0[4]=f2b(x0h.x); vx0[5]=f2b(x0h.y); vx0[6]=f2b(x0h.z); vx0[7]=f2b(x0h.w);
        vx1[0]=f2b(x1l.x); vx1[1]=f2b(x1l.y); vx1[2]=f2b(x1l.z); vx1[3]=f2b(x1l.w);
        vx1[4]=f2b(x1h.x); vx1[5]=f2b(x1h.y); vx1[6]=f2b(x1h.z); vx1[7]=f2b(x1h.w);
        __syncthreads();
        *(bf16x8*)(Xs + wo0) = vx0;
        *(bf16x8*)(Xs + wo1) = vx1;
        *(bf16x8*)(Ws + wo0) = w0;
        *(bf16x8*)(Ws + wo1) = w1;
        __syncthreads();
        if (ks + 1 < nsteps){
            pX0 += 32; pX1 += 32; pW0 += 32; pW1 += 32;
            x0l = *(const float4*)pX0; x0h = *(const float4*)(pX0+4);
            x1l = *(const float4*)pX1; x1h = *(const float4*)(pX1+4);
            w0 = *(const bf16x8*)pW0;  w1 = *(const bf16x8*)pW1;
        }
        bf16x8 wf[4], xf[4];
#pragma unroll
        for (int f = 0; f < 4; f++){
            wf[f] = *(const bf16x8*)(Ws + rwOff[f]);
            xf[f] = *(const bf16x8*)(Xs + rxOff[f]);
        }
#pragma unroll
        for (int i = 0; i < 4; i++)
#pragma unroll
            for (int j = 0; j < 4; j++)
                acc[i][j] = __builtin_amdgcn_mfma_f32_16x16x32_bf16(wf[i], xf[j], acc[i][j], 0, 0, 0);
    }

    const int mc = wM + (lane & 15);
    const int ncb = wN + ((lane >> 4) << 2);
#pragma unroll
    for (int j = 0; j < 4; j++){
        int row = m0 + mc + j*16;
#pragma unroll
        for (int i = 0; i < 4; i++){
            int col = n0 + ncb + i*16;
            f32x4 v = acc[i][j];
            float4 b4 = *(const float4*)&bias[col];
            short4 xv = *(const short4*)&xb[(size_t)row*N + col];
            short4 sv = { f2b(lrelu(v[0] + b4.x) + b2f(xv.x)),
                          f2b(lrelu(v[1] + b4.y) + b2f(xv.y)),
                          f2b(lrelu(v[2] + b4.z) + b2f(xv.z)),
                          f2b(lrelu(v[3] + b4.w) + b2f(xv.w)) };
            *(short4*)&Yb[(size_t)row*N + col] = sv;
        }
    }
}

// split-K reduce (bf16 partials) + bias + lrelu + fused BN stats -> slot region
__global__ void reduce8s(const __hip_bfloat16* __restrict__ part, const float* __restrict__ bias,
                         float* __restrict__ out, int nf4, int parts, float* __restrict__ slots){
    int tid = threadIdx.x;
    int i = blockIdx.x*256 + tid;
    const short4* p4 = (const short4*)part;
    short4 v0 = p4[i];
    float4 s = { b2f(v0.x), b2f(v0.y), b2f(v0.z), b2f(v0.w) };
    for (int z = 1; z < parts; z++){
        short4 p = p4[(size_t)z*nf4 + i];
        s.x += b2f(p.x); s.y += b2f(p.y); s.z += b2f(p.z); s.w += b2f(p.w);
    }
    int c0 = (i & 31) << 2;
    s.x = lrelu(s.x + bias[c0+0]); s.y = lrelu(s.y + bias[c0+1]);
    s.z = lrelu(s.z + bias[c0+2]); s.w = lrelu(s.w + bias[c0+3]);
    ((float4*)out)[i] = s;
    __shared__ float S[128], Q[128];
    if (tid < 128){ S[tid] = 0.f; Q[tid] = 0.f; }
    __syncthreads();
    atomicAdd(&S[c0+0], s.x); atomicAdd(&Q[c0+0], s.x*s.x);
    atomicAdd(&S[c0+1], s.y); atomicAdd(&Q[c0+1], s.y*s.y);
    atomicAdd(&S[c0+2], s.z); atomicAdd(&Q[c0+2], s.z*s.z);
    atomicAdd(&S[c0+3], s.w); atomicAdd(&Q[c0+3], s.w*s.w);
    __syncthreads();
    if (tid < 128){
        int slot = blockIdx.x & (NSLOT-1);
        atomicAdd(&slots[slot*256 + tid], S[tid]);
        atomicAdd(&slots[slot*256 + 128 + tid], Q[tid]);
    }
}

// ---------------------------------------------------------------- BN
__global__ void bn_stats_v2(const float* __restrict__ x, float* __restrict__ slots, int rows){
    int cg = threadIdx.x & 31, rg = threadIdx.x >> 5;
    float4 s = {0,0,0,0}, q = {0,0,0,0};
    for (int r = blockIdx.x*8 + rg; r < rows; r += gridDim.x*8){
        float4 v = ((const float4*)x)[(size_t)r*32 + cg];
        s.x += v.x; q.x += v.x*v.x;
        s.y += v.y; q.y += v.y*v.y;
        s.z += v.z; q.z += v.z*v.z;
        s.w += v.w; q.w += v.w*v.w;
    }
    __shared__ float S[128], Q[128];
    if (threadIdx.x < 128){ S[threadIdx.x] = 0.f; Q[threadIdx.x] = 0.f; }
    __syncthreads();
    int c0 = cg << 2;
    atomicAdd(&S[c0+0], s.x); atomicAdd(&Q[c0+0], q.x);
    atomicAdd(&S[c0+1], s.y); atomicAdd(&Q[c0+1], q.y);
    atomicAdd(&S[c0+2], s.z); atomicAdd(&Q[c0+2], q.z);
    atomicAdd(&S[c0+3], s.w); atomicAdd(&Q[c0+3], q.w);
    __syncthreads();
    if (threadIdx.x < 128){
        int slot = blockIdx.x & (NSLOT-1);
        atomicAdd(&slots[slot*256 + threadIdx.x], S[threadIdx.x]);
        atomicAdd(&slots[slot*256 + 128 + threadIdx.x], Q[threadIdx.x]);
    }
}

// plain finalize (BN3's coef consumed by gemm_nt8)
__global__ void bn_finalize2(const float* __restrict__ slots,
                             const float* __restrict__ g, const float* __restrict__ b,
                             float invR, float* __restrict__ coef){
    int c = threadIdx.x;
    float s = 0.f, q = 0.f;
    for (int k = 0; k < NSLOT; k++){ s += slots[k*256 + c]; q += slots[k*256 + 128 + c]; }
    float m = s*invR;
    float v = q*invR - m*m;
    float sc = g[c]*rsqrtf(v + EPSV);
    coef[c] = sc;
    coef[128 + c] = b[c] - m*sc;
}

// fused finalize + apply: every block derives coef from slots in LDS, then applies
__global__ __launch_bounds__(256) void bn_apply4f(
    float4* __restrict__ x, const float* __restrict__ slots,
    const float* __restrict__ g, const float* __restrict__ b, float invR, size_t n4)
{
    __shared__ float sc[128], sh[128];
    int tid = threadIdx.x;
    if (tid < 128){
        float s = 0.f, q = 0.f;
        for (int k = 0; k < NSLOT; k++){ s += slots[k*256 + tid]; q += slots[k*256 + 128 + tid]; }
        float m = s*invR;
        float v = q*invR - m*m;
        float scale = g[tid]*rsqrtf(v + EPSV);
        sc[tid] = scale;
        sh[tid] = b[tid] - m*scale;
    }
    __syncthreads();
    size_t i = (size_t)blockIdx.x*blockDim.x + tid;
    size_t stride = (size_t)gridDim.x*blockDim.x;
    for (; i < n4; i += stride){
        int c0 = (int)(i & 31) * 4;
        float4 v = x[i];
        v.x = v.x*sc[c0+0] + sh[c0+0];
        v.y = v.y*sc[c0+1] + sh[c0+1];
        v.z = v.z*sc[c0+2] + sh[c0+2];
        v.w = v.w*sc[c0+3] + sh[c0+3];
        x[i] = v;
    }
}

// ---------------------------------------------------------------- final stage streaming on y (bf16)
__global__ __launch_bounds__(256) void final_stats2(
    const bf16x8* __restrict__ yb, float* __restrict__ slots, int n8)
{
    int tid = threadIdx.x;
    float s[8] = {0,0,0,0,0,0,0,0}, q[8] = {0,0,0,0,0,0,0,0};
    int stride = gridDim.x*256;
    for (int i = blockIdx.x*256 + tid; i < n8; i += stride){
        bf16x8 yv = yb[i];
#pragma unroll
        for (int j = 0; j < 8; j++){
            float y = b2f(yv[j]);
            s[j] += y; q[j] += y*y;
        }
    }
    __shared__ float S[128], Q[128];
    if (tid < 128){ S[tid] = 0.f; Q[tid] = 0.f; }
    __syncthreads();
    int c0 = (tid & 15) << 3;
#pragma unroll
    for (int j = 0; j < 8; j++){
        atomicAdd(&S[c0+j], s[j]);
        atomicAdd(&Q[c0+j], q[j]);
    }
    __syncthreads();
    if (tid < 128){
        int slot = blockIdx.x & (NSLOT-1);
        atomicAdd(&slots[slot*256 + tid], S[tid]);
        atomicAdd(&slots[slot*256 + 128 + tid], Q[tid]);
    }
}

// fused finalize + apply for the final BN (stats over (N,T))
__global__ __launch_bounds__(256) void final_apply2f(
    const bf16x8* __restrict__ yb, const float* __restrict__ slots,
    const float* __restrict__ g, const float* __restrict__ b, float invR,
    float4* __restrict__ out, int n8)
{
    __shared__ float scL[128], shL[128];
    int tid = threadIdx.x;
    if (tid < 128){
        float s = 0.f, q = 0.f;
        for (int k = 0; k < NSLOT; k++){ s += slots[k*256 + tid]; q += slots[k*256 + 128 + tid]; }
        float m = s*invR;
        float v = q*invR - m*m;
        float scale = g[tid]*rsqrtf(v + EPSV);
        scL[tid] = scale;
        shL[tid] = b[tid] - m*scale;
    }
    __syncthreads();
    int c0 = (tid & 15) << 3;
    float sc[8], sh[8];
#pragma unroll
    for (int j = 0; j < 8; j++){ sc[j] = scL[c0+j]; sh[j] = shL[c0+j]; }
    int stride = gridDim.x*256;
    for (int i = blockIdx.x*256 + tid; i < n8; i += stride){
        bf16x8 yv = yb[i];
        float4 lo, hi;
        lo.x = b2f(yv[0])*sc[0] + sh[0];
        lo.y = b2f(yv[1])*sc[1] + sh[1];
        lo.z = b2f(yv[2])*sc[2] + sh[2];
        lo.w = b2f(yv[3])*sc[3] + sh[3];
        hi.x = b2f(yv[4])*sc[4] + sh[4];
        hi.y = b2f(yv[5])*sc[5] + sh[5];
        hi.z = b2f(yv[6])*sc[6] + sh[6];
        hi.w = b2f(yv[7])*sc[7] + sh[7];
        out[2*i]   = lo;
        out[2*i+1] = hi;
    }
}

// ---------------------------------------------------------------- segment ops
__global__ void seg_sum_edge(const int* __restrict__ eoff, const int* __restrict__ enode,
                             const float* __restrict__ h, float* __restrict__ out){
    int m = blockIdx.x, t = threadIdx.x;   // 128
    int jg = t >> 5, cq = t & 31;
    int s0 = eoff[m], cnt = eoff[m+1] - s0;
    __shared__ int sn[128];
    __shared__ float4 comb[4][32];
    float4 acc = {0,0,0,0};
    for (int base = 0; base < cnt; base += 128){
        int i = base + t;
        if (i < cnt) sn[t] = enode[s0+i];
        __syncthreads();
        int lim = min(128, cnt - base);
        for (int j = jg; j < lim; j += 4){
            float4 v = *(const float4*)&h[(size_t)sn[j]*128 + cq*4];
            acc.x += v.x; acc.y += v.y; acc.z += v.z; acc.w += v.w;
        }
        __syncthreads();
    }
    comb[jg][cq] = acc;
    __syncthreads();
    if (t < 32){
        float4 a = comb[0][t], b = comb[1][t], c = comb[2][t], d = comb[3][t];
        float4 tot = { a.x+b.x+c.x+d.x, a.y+b.y+c.y+d.y, a.z+b.z+c.z+d.z, a.w+b.w+c.w+d.w };
        *(float4*)&out[(size_t)m*128 + t*4] = tot;
    }
}

// fused softmax + eo, heads=4 (256 threads; eo laid out [m][c][h])
__global__ void seg_soft_eo4(const int* __restrict__ eoff, const int* __restrict__ eperm,
                             const int* __restrict__ enode,
                             const float* __restrict__ ax, const float* __restrict__ ae,
                             float* __restrict__ alpha, const __hip_bfloat16* __restrict__ xt,
                             float* __restrict__ eo){
    int m = blockIdx.x, t = threadIdx.x;   // 256
    int s0 = eoff[m], cnt = eoff[m+1] - s0;
    __shared__ float red[256];
    if (cnt == 0){
        if (t < 128) *(float4*)&eo[(size_t)m*512 + t*4] = (float4){0,0,0,0};
        return;
    }
    float aeh[4];
#pragma unroll
    for (int h = 0; h < 4; h++) aeh[h] = ae[m*4 + h];
    float lmax[4] = {-1e30f, -1e30f, -1e30f, -1e30f};
    for (int i = t; i < cnt; i += 256){
        int k = eperm[s0+i]; int n = enode[s0+i];
#pragma unroll
        for (int h = 0; h < 4; h++){
            float v = lrelu(ax[n*4 + h] + aeh[h]);
            alpha[(size_t)k*4 + h] = v;
            lmax[h] = fmaxf(lmax[h], v);
        }
    }
    float gmax[4];
#pragma unroll
    for (int h = 0; h < 4; h++){
        red[t] = lmax[h]; __syncthreads();
        for (int s = 128; s > 0; s >>= 1){ if (t < s) red[t] = fmaxf(red[t], red[t+s]); __syncthreads(); }
        gmax[h] = red[0]; __syncthreads();
    }
    float lsum[4] = {0.f, 0.f, 0.f, 0.f};
    for (int i = t; i < cnt; i += 256){
        int k = eperm[s0+i];
#pragma unroll
        for (int h = 0; h < 4; h++){
            float ex = __expf(alpha[(size_t)k*4 + h] - gmax[h]);
            alpha[(size_t)k*4 + h] = ex;
            lsum[h] += ex;
        }
    }
    float ginv[4];
#pragma unroll
    for (int h = 0; h < 4; h++){
        red[t] = lsum[h]; __syncthreads();
        for (int s = 128; s > 0; s >>= 1){ if (t < s) red[t] += red[t+s]; __syncthreads(); }
        ginv[h] = 1.f/red[0]; __syncthreads();
    }
    for (int i = t; i < cnt; i += 256){
        int k = eperm[s0+i];
#pragma unroll
        for (int h = 0; h < 4; h++) alpha[(size_t)k*4 + h] *= ginv[h];
    }
    __syncthreads();
    int jpar = t >> 7, cq = t & 127;
    int hq = cq >> 5;
    __shared__ int sn[128];
    __shared__ float sa[128][4];
    __shared__ float comb[256][4];
    float acc[4] = {0.f, 0.f, 0.f, 0.f};
    for (int base = 0; base < cnt; base += 128){
        int i = base + t;
        if (t < 128 && i < cnt){
            sn[t] = enode[s0+i];
            *(float4*)sa[t] = *(const float4*)&alpha[(size_t)eperm[s0+i]*4];
        }
        __syncthreads();
        int lim = min(128, cnt - base);
        for (int j = jpar; j < lim; j += 2){
            const ushort* p = (const ushort*)xt + (size_t)sn[j]*512 + cq*4;
            ushort4 u = *(const ushort4*)p;
            float a = sa[j][hq];
            acc[0] += a*b2f((short)u.x); acc[1] += a*b2f((short)u.y);
            acc[2] += a*b2f((short)u.z); acc[3] += a*b2f((short)u.w);
        }
        __syncthreads();
    }
    comb[t][0] = acc[0]; comb[t][1] = acc[1]; comb[t][2] = acc[2]; comb[t][3] = acc[3];
    __syncthreads();
    if (t < 128){
        float binv = 1.f/(float)cnt;
#pragma unroll
        for (int i2 = 0; i2 < 4; i2++){
            int ch = t*4 + i2;
            int h = ch >> 7, c = ch & 127;
            eo[(size_t)m*512 + c*4 + h] = (comb[t][i2] + comb[t+128][i2]) * binv;
        }
    }
}

// fused softmax + eo, heads=1 (128 threads)
__global__ void seg_soft_eo1(const int* __restrict__ eoff, const int* __restrict__ eperm,
                             const int* __restrict__ enode,
                             const float* __restrict__ ax, const float* __restrict__ ae,
                             float* __restrict__ alpha, const __hip_bfloat16* __restrict__ xt,
                             float* __restrict__ eo){
    int m = blockIdx.x, t = threadIdx.x;   // 128
    int s0 = eoff[m], cnt = eoff[m+1] - s0;
    __shared__ float red[128];
    if (cnt == 0){
        if (t < 32) *(float4*)&eo[(size_t)m*128 + t*4] = (float4){0,0,0,0};
        return;
    }
    float aeh = ae[m];
    float lmax = -1e30f;
    for (int i = t; i < cnt; i += 128){
        int k = eperm[s0+i]; int n = enode[s0+i];
        float v = lrelu(ax[n] + aeh);
        alpha[k] = v;
        lmax = fmaxf(lmax, v);
    }
    red[t] = lmax; __syncthreads();
    for (int s = 64; s > 0; s >>= 1){ if (t < s) red[t] = fmaxf(red[t], red[t+s]); __syncthreads(); }
    float gmax = red[0]; __syncthreads();
    float lsum = 0.f;
    for (int i = t; i < cnt; i += 128){
        int k = eperm[s0+i];
        float ex = __expf(alpha[k] - gmax);
        alpha[k] = ex;
        lsum += ex;
    }
    red[t] = lsum; __syncthreads();
    for (int s = 64; s > 0; s >>= 1){ if (t < s) red[t] += red[t+s]; __syncthreads(); }
    float ginv = 1.f/red[0]; __syncthreads();
    for (int i = t; i < cnt; i += 128){
        int k = eperm[s0+i];
        alpha[k] *= ginv;
    }
    __syncthreads();
    int jg = t >> 5, cq = t & 31;
    __shared__ int sn[128];
    __shared__ float sa[128];
    __shared__ float4 comb[4][32];
    float4 acc = {0,0,0,0};
    for (int base = 0; base < cnt; base += 128){
        int i = base + t;
        if (i < cnt){
            sn[t] = enode[s0+i];
            sa[t] = alpha[eperm[s0+i]];
        }
        __syncthreads();
        int lim = min(128, cnt - base);
        for (int j = jg; j < lim; j += 4){
            const ushort* p = (const ushort*)xt + (size_t)sn[j]*128 + cq*4;
            ushort4 u = *(const ushort4*)p;
            float a = sa[j];
            acc.x += a*b2f((short)u.x); acc.y += a*b2f((short)u.y);
            acc.z += a*b2f((short)u.z); acc.w += a*b2f((short)u.w);
        }
        __syncthreads();
    }
    comb[jg][cq] = acc;
    __syncthreads();
    if (t < 32){
        float binv = 1.f/(float)cnt;
        float4 a = comb[0][t], b = comb[1][t], c = comb[2][t], d = comb[3][t];
        float4 tot = { (a.x+b.x+c.x+d.x)*binv, (a.y+b.y+c.y+d.y)*binv,
                       (a.z+b.z+c.z+d.z)*binv, (a.w+b.w+c.w+d.w)*binv };
        *(float4*)&eo[(size_t)m*128 + t*4] = tot;
    }
}

__global__ void seg_node_out4(const int* __restrict__ noff, const int* __restrict__ nperm,
                              const int* __restrict__ nedge,
                              const float* __restrict__ alpha, const float* __restrict__ eo,
                              const float* __restrict__ hin, const float* __restrict__ bias,
                              float* __restrict__ hout){
    int n = blockIdx.x, c = threadIdx.x;   // 128
    int s0 = noff[n], cnt = noff[n+1] - s0;
    float acc = 0.f;
    for (int i = 0; i < cnt; i++){
        int k = nperm[s0+i]; int e = nedge[s0+i];
        float4 al = *(const float4*)&alpha[(size_t)k*4];
        float4 ev = *(const float4*)&eo[(size_t)e*512 + c*4];
        acc += al.x*ev.x + al.y*ev.y + al.z*ev.z + al.w*ev.w;
    }
    float dinv = cnt > 0 ? 1.f/((float)cnt*4.f) : 0.f;
    hout[(size_t)n*128 + c] = hin[(size_t)n*128 + c] + bias[c] + acc*dinv;
}

__global__ void seg_node_out1(const int* __restrict__ noff, const int* __restrict__ nperm,
                              const int* __restrict__ nedge,
                              const float* __restrict__ alpha, const float* __restrict__ eo,
                              const float* __restrict__ hin, const float* __restrict__ bias,
                              float* __restrict__ hout){
    int n = blockIdx.x, c = threadIdx.x;
    int s0 = noff[n], cnt = noff[n+1] - s0;
    float acc = 0.f;
    for (int i = 0; i < cnt; i++){
        int k = nperm[s0+i]; int e = nedge[s0+i];
        acc += alpha[k]*eo[(size_t)e*128 + c];
    }
    float dinv = cnt > 0 ? 1.f/(float)cnt : 0.f;
    hout[(size_t)n*128 + c] = hin[(size_t)n*128 + c] + bias[c] + acc*dinv;
}

// ---------------------------------------------------------------- launcher
extern "C" void kernel_launch(void* const* d_in, const int* in_sizes, int n_in,
                              void* d_out, int out_size, void* d_ws, size_t ws_size,
                              hipStream_t stream){
    const float* x    = (const float*)d_in[0];
    const int*   he_n = (const int*)  d_in[1];
    const int*   he_e = (const int*)  d_in[2];
    const float* W1   = (const float*)d_in[3];
    const float* b1   = (const float*)d_in[4];
    const float* g1   = (const float*)d_in[5];
    const float* be1  = (const float*)d_in[6];
    const float* Wh1  = (const float*)d_in[7];
    const float* att1 = (const float*)d_in[8];
    const float* bh1  = (const float*)d_in[9];
    const float* g2   = (const float*)d_in[10];
    const float* be2  = (const float*)d_in[11];
    const float* Wh2  = (const float*)d_in[12];
    const float* att2 = (const float*)d_in[13];
    const float* bh2  = (const float*)d_in[14];
    const float* g3   = (const float*)d_in[15];
    const float* be3  = (const float*)d_in[16];
    const float* W3   = (const float*)d_in[17];
    const float* b3   = (const float*)d_in[18];
    const float* g4   = (const float*)d_in[19];
    const float* be4  = (const float*)d_in[20];
    float* out = (float*)d_out;

    char* ws = (char*)d_ws;
    size_t off = 0;
    auto alloc = [&](size_t bytes)->char*{ char* p = ws + off; off += (bytes + 255) & ~(size_t)255; return p; };

    // big region (64 MB): ybuf (final) aliases part (GEMM1) + xt1b (hconv1)
    char* big = alloc((size_t)NN*DIN*2);
    __hip_bfloat16* ybuf = (__hip_bfloat16*)big;
    __hip_bfloat16* part = (__hip_bfloat16*)big;
    __hip_bfloat16* xt1b = (__hip_bfloat16*)(big + (size_t)16*NN*128*2);
    __hip_bfloat16* xbuf = (__hip_bfloat16*)alloc((size_t)NN*DIN*2);

    float* hall1  = (float*)alloc((size_t)MALL*128*4);
    float* hall2  = (float*)alloc((size_t)MALL*128*4);
    float* h3     = (float*)alloc((size_t)NN*128*4);
    __hip_bfloat16* xt2b = (__hip_bfloat16*)alloc((size_t)MALL*128*2);
    float* eo     = (float*)alloc((size_t)MME*512*4);
    float* alpha  = (float*)alloc((size_t)NNZK*4*4);
    float* ax     = (float*)alloc((size_t)NN*4*4);
    float* ae     = (float*)alloc((size_t)MME*4*4);
    float* slots  = (float*)alloc((size_t)4*SLOTREG*4);   // 4 single-use regions
    float* coef   = (float*)alloc(256*4);
    __hip_bfloat16* W1T  = (__hip_bfloat16*)alloc((size_t)128*DIN*2);
    __hip_bfloat16* Wh1T = (__hip_bfloat16*)alloc((size_t)512*128*2);
    __hip_bfloat16* Wh2T = (__hip_bfloat16*)alloc((size_t)128*128*2);
    __hip_bfloat16* W3T  = (__hip_bfloat16*)alloc((size_t)DIN*128*2);
    int* ecnt  = (int*)alloc(MME*4);
    int* ncnt  = (int*)alloc(NN*4);
    int* eoffb = (int*)alloc((MME+1)*4);
    int* ecur  = (int*)alloc(MME*4);
    int* noffb = (int*)alloc((NN+1)*4);
    int* ncur  = (int*)alloc(NN*4);
    int* eperm = (int*)alloc((size_t)NNZK*4);
    int* nperm = (int*)alloc((size_t)NNZK*4);
    int* enode = (int*)alloc((size_t)NNZK*4);
    int* nedge = (int*)alloc((size_t)NNZK*4);

    float* slot0 = slots;
    float* slot1 = slots + SLOTREG;
    float* slot2 = slots + 2*SLOTREG;
    float* slot3 = slots + 3*SLOTREG;

    // ---- zero counters + all slot regions ----
    zero_all<<<(MME+NN+4*SLOTREG+255)/256, 256, 0, stream>>>(ecnt, MME+NN, slots, 4*SLOTREG);

    // ---- setup mega-kernel: x->bf16 | count_seg | weight converts (co-executing) ----
    setup_all<<<3664, 256, 0, stream>>>((const float4*)x, (bf16x8*)xbuf, he_n, he_e, ncnt, ecnt,
                                        W1, W1T, Wh1, Wh1T, Wh2, Wh2T, W3, W3T);

    // ---- CSR ----
    scan2<<<2, 1024, 0, stream>>>(ecnt, eoffb, ecur, ncnt, noffb, ncur);
    fill_both<<<NNZK/256, 256, 0, stream>>>(he_n, he_e, ecur, ncur, eperm, enode, nperm, nedge);

    // ---- layer 0 ----
    gemm_bb<<<dim3(1, NN/128, 16), 256, 0, stream>>>(xbuf, W1T, part, NN, 128, DIN, DIN/16);
    reduce8s<<<NN*128/4/256, 256, 0, stream>>>(part, b1, hall1, NN*128/4, 16, slot0);
    bn_apply4f<<<1024, 256, 0, stream>>>((float4*)hall1, slot0, g1, be1, 1.f/NN, (size_t)NN*32);

    // ---- hconv1 (heads=4) ----
    seg_sum_edge<<<MME, 128, 0, stream>>>(eoffb, enode, hall1, hall1 + (size_t)NN*128);
    gemm_att<4><<<dim3(4, MALL/128), 256, 0, stream>>>(hall1, Wh1T, xt1b, att1, ax, ae, MALL, 512, 128);
    seg_soft_eo4<<<MME, 256, 0, stream>>>(eoffb, eperm, enode, ax, ae, alpha, xt1b, eo);
    seg_node_out4<<<NN, 128, 0, stream>>>(noffb, nperm, nedge, alpha, eo, hall1, bh1, hall2);
    bn_stats_v2<<<256, 256, 0, stream>>>(hall2, slot1, NN);
    bn_apply4f<<<1024, 256, 0, stream>>>((float4*)hall2, slot1, g2, be2, 1.f/NN, (size_t)NN*32);

    // ---- hconv2 (heads=1) ----
    seg_sum_edge<<<MME, 128, 0, stream>>>(eoffb, enode, hall2, hall2 + (size_t)NN*128);
    gemm_att<1><<<dim3(1, MALL/128), 256, 0, stream>>>(hall2, Wh2T, xt2b, att2, ax, ae, MALL, 128, 128);
    seg_soft_eo1<<<MME, 128, 0, stream>>>(eoffb, eperm, enode, ax, ae, alpha, xt2b, eo);
    seg_node_out1<<<NN, 128, 0, stream>>>(noffb, nperm, nedge, alpha, eo, hall2, bh2, h3);

    // ---- BN3 stats (apply folded into GEMM3 staging) ----
    bn_stats_v2<<<256, 256, 0, stream>>>(h3, slot2, NN);
    bn_finalize2<<<1, 128, 0, stream>>>(slot2, g3, be3, 1.f/NN, coef);

    // ---- final ----
    gemm_nt8<<<dim3(DIN/128, NN/128), 256, 0, stream>>>(h3, W3T, xbuf, ybuf, b3, coef, NN, DIN, 128);
    final_stats2<<<2048, 256, 0, stream>>>((const bf16x8*)ybuf, slot3, NN*DIN/8);
    final_apply2f<<<2048, 256, 0, stream>>>((const bf16x8*)ybuf, slot3, g4, be4,
                                            1.f/((float)NN*TT), (float4*)out, NN*DIN/8);
}